// Round 6
// baseline (202.956 us; speedup 1.0000x reference)
//
#include <hip/hip_runtime.h>
#include <math.h>

#define LN_EPS 1e-3f

typedef __attribute__((ext_vector_type(8))) short short8;
typedef __attribute__((ext_vector_type(4))) float floatx4;

__device__ __forceinline__ float silu_f(float x) { return x / (1.f + expf(-x)); }

__device__ __forceinline__ int mism1(float a, float s) {
    unsigned ua = __float_as_uint(a);
    unsigned ub = __float_as_uint(a + s);
    return (int)((ua ^ ub) >> 31);
}

__device__ __forceinline__ short f2bf(float f) {
    unsigned u = __float_as_uint(f);
    unsigned r = (u + 0x7FFFu + ((u >> 16) & 1u)) >> 16;
    return (short)r;
}

// ---------------- Kernel 0: swizzle conv1 + conv2 weights into B-fragment bf16
// w1s[kc(8)][ks(10)][nt(8)][lane(64)][j(8)]  (327,680)
// w2s[ks(12)][nt(64)][lane(64)][j(8)]        (393,216)
__global__ __launch_bounds__(256) void k_prep(
    const float* __restrict__ w1,   // (5,512,128)
    const float* __restrict__ w2,   // (3,128,1024)
    short* __restrict__ w1s,
    short* __restrict__ w2s)
{
    int tid = blockIdx.x * 256 + threadIdx.x;
    if (tid < 327680) {
        int j    = tid & 7;
        int lane = (tid >> 3) & 63;
        int nt   = (tid >> 9) & 7;
        int ks   = (tid >> 12) % 10;
        int kc   = tid / 40960;
        int kw = ks >> 1;
        int ci = kc * 64 + (ks & 1) * 32 + ((lane >> 4) & 3) * 8 + j;
        int n  = nt * 16 + (lane & 15);
        w1s[tid] = f2bf(w1[((size_t)(kw * 512 + ci)) * 128 + n]);
    } else {
        int t = tid - 327680;
        if (t < 393216) {
            int j    = t & 7;
            int lane = (t >> 3) & 63;
            int nt   = (t >> 9) & 63;
            int ks   = t >> 15;                 // 0..11
            int k  = ks * 32 + ((lane >> 4) & 3) * 8 + j;   // 0..383
            int kw = k >> 7;
            int ci = k & 127;
            int n  = nt * 16 + (lane & 15);
            w2s[t] = f2bf(w2[((size_t)(kw * 128 + ci)) * 1024 + n]);
        }
    }
}

// ---------------- Kernel 1: conv1 as bf16 MFMA GEMM, split-K over 8 ci-chunks
// grid = 50 Mtiles(64 pos) * 8 kc = 400 blocks, 256 threads (4 waves, 2x2).
__global__ __launch_bounds__(256) void k_conv1m(
    const float* __restrict__ values,   // (4,1920,512)
    const float* __restrict__ symbols,  // (1920,512)
    const short* __restrict__ w1s,
    float* __restrict__ part)           // (8,3200,128)
{
    int kc = blockIdx.x & 7;
    int mt = blockIdx.x >> 3;            // 0..49
    int seq = mt / 10;
    int t0  = (mt % 10) * 64;
    const float* x = (seq < 4) ? (values + (size_t)seq * 1920 * 512) : symbols;
    int p0 = 3 * t0 - 1;

    __shared__ short xs[194 * 72];

    int tid = threadIdx.x;
    for (int idx = tid; idx < 194 * 16; idx += 256) {
        int r = idx >> 4, g = idx & 15;
        int gp = p0 + r;
        float4 v = make_float4(0.f, 0.f, 0.f, 0.f);
        if (gp >= 0 && gp < 1920)
            v = *(const float4*)(x + (size_t)gp * 512 + kc * 64 + 4 * g);
        short* d = xs + r * 72 + 4 * g;
        d[0] = f2bf(v.x); d[1] = f2bf(v.y); d[2] = f2bf(v.z); d[3] = f2bf(v.w);
    }
    __syncthreads();

    int lane = tid & 63;
    int w    = tid >> 6;
    int wm   = w & 1;
    int wn   = w >> 1;
    int quad = lane >> 4;
    int mrow = lane & 15;

    floatx4 acc[2][4];
    #pragma unroll
    for (int mi = 0; mi < 2; mi++)
        #pragma unroll
        for (int ni = 0; ni < 4; ni++)
            acc[mi][ni] = (floatx4){0.f, 0.f, 0.f, 0.f};

    #pragma unroll 2
    for (int ks = 0; ks < 10; ks++) {
        int kw  = ks >> 1;
        int ci0 = (ks & 1) * 32;
        short8 a[2];
        #pragma unroll
        for (int mi = 0; mi < 2; mi++) {
            int r = 3 * (wm * 32 + mi * 16 + mrow) + kw;
            a[mi] = *(const short8*)(xs + r * 72 + ci0 + quad * 8);
        }
        #pragma unroll
        for (int ni = 0; ni < 4; ni++) {
            int nt = wn * 4 + ni;
            short8 b = *(const short8*)(w1s +
                ((((size_t)kc * 10 + ks) * 8 + nt) * 64 + lane) * 8);
            #pragma unroll
            for (int mi = 0; mi < 2; mi++)
                acc[mi][ni] = __builtin_amdgcn_mfma_f32_16x16x32_bf16(
                    a[mi], b, acc[mi][ni], 0, 0, 0);
        }
    }

    #pragma unroll
    for (int mi = 0; mi < 2; mi++) {
        #pragma unroll
        for (int ni = 0; ni < 4; ni++) {
            int co = wn * 64 + ni * 16 + mrow;
            #pragma unroll
            for (int reg = 0; reg < 4; reg++) {
                int pos = mt * 64 + wm * 32 + mi * 16 + quad * 4 + reg;
                part[((size_t)kc * 3200 + pos) * 128 + co] = acc[mi][ni][reg];
            }
        }
    }
}

// ---------------- Kernel 2: fused [part-reduce + LN1 + SiLU] -> bf16 LDS im2col
// -> conv2 MFMA (16 pos x 1024 co) -> LN2 + SiLU -> vp / sp.
// grid = 40 blocks (8 row-blocks x 5 seq), 256 threads (4 waves, n-split).
__global__ __launch_bounds__(256) void k_conv2m(
    const float* __restrict__ part,  // (8,3200,128)
    const float* __restrict__ b1,
    const float* __restrict__ g1,
    const float* __restrict__ bt1,
    const short* __restrict__ w2s,
    const float* __restrict__ b2,
    const float* __restrict__ g2,
    const float* __restrict__ bt2,
    float* __restrict__ vp,          // (512,1024)
    float* __restrict__ sp)          // (128,1024)
{
    int blk = blockIdx.x;            // 0..39
    int seq = blk >> 3;
    int rb  = blk & 7;
    int row0 = seq * 640 + rb * 80;  // h1-row base
    int pos0 = seq * 128 + rb * 16;  // output-pos base (0..639)

    __shared__ short xa[78 * 136];   // 78 rows x 128 ci (pitch 136 -> 16B aligned)
    __shared__ float red[4][4][4][2];

    int tid = threadIdx.x;

    // ---- staging: reduce 8 partials + bias1 + LN1(128) + SiLU -> bf16
    for (int idx = tid; idx < 78 * 32; idx += 256) {
        int r = idx >> 5, l = idx & 31;
        int prow = row0 + r;
        float4 a = make_float4(0.f, 0.f, 0.f, 0.f);
        #pragma unroll
        for (int kc = 0; kc < 8; kc++) {
            float4 pv = *(const float4*)(part + ((size_t)kc * 3200 + prow) * 128 + 4 * l);
            a.x += pv.x; a.y += pv.y; a.z += pv.z; a.w += pv.w;
        }
        float4 bias = *(const float4*)(b1 + 4 * l);
        a.x += bias.x; a.y += bias.y; a.z += bias.z; a.w += bias.w;

        float s1 = a.x + a.y + a.z + a.w;
        float s2 = a.x*a.x + a.y*a.y + a.z*a.z + a.w*a.w;
        #pragma unroll
        for (int m = 16; m >= 1; m >>= 1) {
            s1 += __shfl_xor(s1, m, 64);
            s2 += __shfl_xor(s2, m, 64);
        }
        float mean = s1 * (1.f / 128.f);
        float var  = s2 * (1.f / 128.f) - mean * mean;
        float rs   = rsqrtf(var + LN_EPS);
        float4 gam = *(const float4*)(g1 + 4 * l);
        float4 bet = *(const float4*)(bt1 + 4 * l);
        short* d = xa + r * 136 + 4 * l;
        d[0] = f2bf(silu_f((a.x - mean) * rs * gam.x + bet.x));
        d[1] = f2bf(silu_f((a.y - mean) * rs * gam.y + bet.y));
        d[2] = f2bf(silu_f((a.z - mean) * rs * gam.z + bet.z));
        d[3] = f2bf(silu_f((a.w - mean) * rs * gam.w + bet.w));
    }
    __syncthreads();

    // ---- MFMA: A[m=lane&15][k=quad*8+j] (m120), 12 k-steps of 32
    int lane = tid & 63, w = tid >> 6;
    int quad = lane >> 4, mrow = lane & 15;

    floatx4 acc[16];
    #pragma unroll
    for (int nt = 0; nt < 16; nt++) acc[nt] = (floatx4){0.f, 0.f, 0.f, 0.f};

    #pragma unroll 3
    for (int ks = 0; ks < 12; ks++) {
        int kw  = ks >> 2;
        int ci0 = (ks & 3) * 32;
        short8 a = *(const short8*)(xa + (5 * mrow + kw) * 136 + ci0 + quad * 8);
        #pragma unroll
        for (int nt = 0; nt < 16; nt++) {
            short8 b = *(const short8*)(w2s +
                (((size_t)ks * 64 + w * 16 + nt) * 64 + lane) * 8);
            acc[nt] = __builtin_amdgcn_mfma_f32_16x16x32_bf16(a, b, acc[nt], 0, 0, 0);
        }
    }

    // ---- epilogue: bias2, LN2 over 1024, SiLU, store
    float b2v[16], g2v[16], btv[16];
    #pragma unroll
    for (int nt = 0; nt < 16; nt++) {
        int co = w * 256 + nt * 16 + mrow;
        b2v[nt] = b2[co]; g2v[nt] = g2[co]; btv[nt] = bt2[co];
    }

    float s1[4] = {0.f, 0.f, 0.f, 0.f}, s2[4] = {0.f, 0.f, 0.f, 0.f};
    #pragma unroll
    for (int nt = 0; nt < 16; nt++)
        #pragma unroll
        for (int r = 0; r < 4; r++) {
            float v = acc[nt][r] + b2v[nt];
            acc[nt][r] = v;
            s1[r] += v; s2[r] += v * v;
        }
    #pragma unroll
    for (int m = 8; m >= 1; m >>= 1) {
        #pragma unroll
        for (int r = 0; r < 4; r++) {
            s1[r] += __shfl_xor(s1[r], m, 64);
            s2[r] += __shfl_xor(s2[r], m, 64);
        }
    }
    if (mrow == 0) {
        #pragma unroll
        for (int r = 0; r < 4; r++) { red[w][quad][r][0] = s1[r]; red[w][quad][r][1] = s2[r]; }
    }
    __syncthreads();

    float mean[4], rs[4];
    #pragma unroll
    for (int r = 0; r < 4; r++) {
        float S1 = red[0][quad][r][0] + red[1][quad][r][0]
                 + red[2][quad][r][0] + red[3][quad][r][0];
        float S2 = red[0][quad][r][1] + red[1][quad][r][1]
                 + red[2][quad][r][1] + red[3][quad][r][1];
        mean[r] = S1 * (1.f / 1024.f);
        float var = S2 * (1.f / 1024.f) - mean[r] * mean[r];
        rs[r] = rsqrtf(var + LN_EPS);
    }

    bool isv = (seq < 4);
    float* obase = isv ? (vp + ((size_t)pos0) * 1024)
                       : (sp + ((size_t)(pos0 - 512)) * 1024);
    #pragma unroll
    for (int nt = 0; nt < 16; nt++) {
        int co = w * 256 + nt * 16 + mrow;
        #pragma unroll
        for (int r = 0; r < 4; r++) {
            float o = silu_f((acc[nt][r] - mean[r]) * rs[r] * g2v[nt] + btv[nt]);
            obase[((size_t)(quad * 4 + r)) * 1024 + co] = o;
        }
    }
}

// ---------------- Kernel 3: mismatch counts
__global__ __launch_bounds__(256) void k_attn_cnt(
    const float* __restrict__ vp,   // (512,1024)
    const float* __restrict__ sp,   // (128,1024)
    int* __restrict__ cnt)          // (4,128,128)
{
    int b = blockIdx.x >> 7;
    int j = blockIdx.x & 127;
    int tid = threadIdx.x;
    int i = tid & 127, half = tid >> 7;

    const float* vrow = vp + ((size_t)(b * 128 + i)) * 1024 + half * 512;
    const float* srow = sp + (size_t)j * 1024 + half * 512;

    int m = 0;
    #pragma unroll 8
    for (int k = 0; k < 128; k++) {
        float4 v = *(const float4*)(vrow + 4 * k);
        float4 s = *(const float4*)(srow + 4 * k);
        m += mism1(v.x, s.x) + mism1(v.y, s.y) + mism1(v.z, s.z) + mism1(v.w, s.w);
    }

    __shared__ int cc[2][128];
    cc[half][i] = m;
    __syncthreads();
    if (tid < 128)
        cnt[((size_t)b * 128 + j) * 128 + tid] = cc[0][tid] + cc[1][tid];
}

// ---------------- Kernel 4: softmax (per wave) + einsum + silu
__global__ __launch_bounds__(256) void k_attn_out(
    const int*   __restrict__ cnt,  // (4,128,128)
    const float* __restrict__ vp,   // (512,1024)
    const float* __restrict__ sp,   // (128,1024)
    float* __restrict__ O)          // (4,128,1024)
{
    int b  = blockIdx.x >> 7;
    int r  = blockIdx.x & 127;
    int j0 = (r >> 2) * 4;
    int d0 = (r & 3) * 256;
    int tid = threadIdx.x, lane = tid & 63, w = tid >> 6;
    int j = j0 + w;

    __shared__ float sc[4][128];

    const int* crow = cnt + ((size_t)b * 128 + j) * 128;
    int c0 = crow[lane], c1 = crow[lane + 64];
    float S0 = 1.f - (float)c0 * (2.f / 1024.f);
    float S1 = 1.f - (float)c1 * (2.f / 1024.f);
    float mx = fmaxf(S0, S1);
    #pragma unroll
    for (int m = 32; m >= 1; m >>= 1) mx = fmaxf(mx, __shfl_xor(mx, m, 64));
    float e0 = expf(S0 - mx), e1 = expf(S1 - mx);
    float sm = e0 + e1;
    #pragma unroll
    for (int m = 32; m >= 1; m >>= 1) sm += __shfl_xor(sm, m, 64);
    float inv = 1.f / sm;
    sc[w][lane]      = e0 * inv;
    sc[w][lane + 64] = e1 * inv;
    __syncthreads();

    int dd = d0 + 4 * lane;
    const float* vpb = vp + (size_t)b * 131072;
    float4 ao = make_float4(0.f, 0.f, 0.f, 0.f);
    #pragma unroll 4
    for (int i = 0; i < 128; i++) {
        float4 v = *(const float4*)(vpb + (size_t)i * 1024 + dd);
        float f = sc[w][i];
        ao.x += f * v.x; ao.y += f * v.y; ao.z += f * v.z; ao.w += f * v.w;
    }
    float4 s = *(const float4*)(sp + (size_t)j * 1024 + dd);
    float4 o;
    o.x = silu_f(ao.x * s.x);
    o.y = silu_f(ao.y * s.y);
    o.z = silu_f(ao.z * s.z);
    o.w = silu_f(ao.w * s.w);
    *(float4*)(O + ((size_t)b * 128 + j) * 1024 + dd) = o;
}

extern "C" void kernel_launch(void* const* d_in, const int* in_sizes, int n_in,
                              void* d_out, int out_size, void* d_ws, size_t ws_size,
                              hipStream_t stream) {
    const float* values  = (const float*)d_in[0];
    const float* symbols = (const float*)d_in[1];
    const float* conv1_w = (const float*)d_in[2];
    const float* conv1_b = (const float*)d_in[3];
    const float* ln1_g   = (const float*)d_in[4];
    const float* ln1_b   = (const float*)d_in[5];
    const float* conv2_w = (const float*)d_in[6];
    const float* conv2_b = (const float*)d_in[7];
    const float* ln2_g   = (const float*)d_in[8];
    const float* ln2_b   = (const float*)d_in[9];

    float* out = (float*)d_out;
    float* O   = out;                       // (4,128,1024)
    float* vp  = out + 4 * 128 * 1024;      // (4,128,1024)

    float* part = (float*)d_ws;             // (8,3200,128)  = 3,276,800 f
    float* sp   = part + 8 * 3200 * 128;    // (128,1024)
    int*   cnt  = (int*)(sp + 128 * 1024);  // (4,128,128)
    short* w1s  = (short*)(cnt + 4 * 128 * 128);   // 327,680
    short* w2s  = w1s + 327680;                    // 393,216

    k_prep<<<2816, 256, 0, stream>>>(conv1_w, conv2_w, w1s, w2s);
    k_conv1m<<<400, 256, 0, stream>>>(values, symbols, w1s, part);
    k_conv2m<<<40, 256, 0, stream>>>(part, conv1_b, ln1_g, ln1_b,
                                     w2s, conv2_b, ln2_g, ln2_b, vp, sp);
    k_attn_cnt<<<512, 256, 0, stream>>>(vp, sp, cnt);
    k_attn_out<<<512, 256, 0, stream>>>(cnt, vp, sp, O);
}

// Round 7
// 178.498 us; speedup vs baseline: 1.1370x; 1.1370x over previous
//
#include <hip/hip_runtime.h>
#include <math.h>

#define LN_EPS 1e-3f

typedef __attribute__((ext_vector_type(8))) short short8;
typedef __attribute__((ext_vector_type(4))) float floatx4;

__device__ __forceinline__ float silu_f(float x) { return x / (1.f + expf(-x)); }

__device__ __forceinline__ int mism1(float a, float s) {
    unsigned ua = __float_as_uint(a);
    unsigned ub = __float_as_uint(a + s);
    return (int)((ua ^ ub) >> 31);
}

__device__ __forceinline__ short f2bf(float f) {
    unsigned u = __float_as_uint(f);
    unsigned r = (u + 0x7FFFu + ((u >> 16) & 1u)) >> 16;
    return (short)r;
}

// ---------------- Kernel 0: swizzle conv1 + conv2 weights into B-fragment bf16
// w1s[kc(8)][ks(10)][nt(8)][lane(64)][j(8)]  (327,680)
// w2s[ks(12)][nt(64)][lane(64)][j(8)]        (393,216)
__global__ __launch_bounds__(256) void k_prep(
    const float* __restrict__ w1,   // (5,512,128)
    const float* __restrict__ w2,   // (3,128,1024)
    short* __restrict__ w1s,
    short* __restrict__ w2s)
{
    int tid = blockIdx.x * 256 + threadIdx.x;
    if (tid < 327680) {
        int j    = tid & 7;
        int lane = (tid >> 3) & 63;
        int nt   = (tid >> 9) & 7;
        int ks   = (tid >> 12) % 10;
        int kc   = tid / 40960;
        int kw = ks >> 1;
        int ci = kc * 64 + (ks & 1) * 32 + ((lane >> 4) & 3) * 8 + j;
        int n  = nt * 16 + (lane & 15);
        w1s[tid] = f2bf(w1[((size_t)(kw * 512 + ci)) * 128 + n]);
    } else {
        int t = tid - 327680;
        if (t < 393216) {
            int j    = t & 7;
            int lane = (t >> 3) & 63;
            int nt   = (t >> 9) & 63;
            int ks   = t >> 15;                 // 0..11
            int k  = ks * 32 + ((lane >> 4) & 3) * 8 + j;   // 0..383
            int kw = k >> 7;
            int ci = k & 127;
            int n  = nt * 16 + (lane & 15);
            w2s[t] = f2bf(w2[((size_t)(kw * 128 + ci)) * 1024 + n]);
        }
    }
}

// ---------------- Kernel 1: conv1 full-K MFMA GEMM + bias + LN1(128) + SiLU -> h1 bf16
// grid = 200 blocks (5 seq * 40 tiles of 16 pos), 256 threads (4 waves).
// Block computes 16 pos x 128 co; wave w covers co [32w, 32w+32).
__global__ __launch_bounds__(256) void k_conv1m(
    const float* __restrict__ values,   // (4,1920,512)
    const float* __restrict__ symbols,  // (1920,512)
    const short* __restrict__ w1s,
    const float* __restrict__ b1,
    const float* __restrict__ g1,
    const float* __restrict__ bt1,
    short* __restrict__ h1)             // (3200,128) bf16
{
    int mt  = blockIdx.x;               // 0..199
    int seq = mt / 40;
    int tl  = mt % 40;                  // tile within seq, 16 pos each
    const float* x = (seq < 4) ? (values + (size_t)seq * 1920 * 512) : symbols;
    int p0 = 3 * (tl * 16) - 1;

    __shared__ short xs[50 * 72];       // 50 input rows x 64 ci (+8 pad)
    __shared__ float red[4][4][4][2];

    int tid  = threadIdx.x;
    int lane = tid & 63, w = tid >> 6;
    int quad = lane >> 4, mrow = lane & 15;

    floatx4 acc[2];
    acc[0] = (floatx4){0.f, 0.f, 0.f, 0.f};
    acc[1] = (floatx4){0.f, 0.f, 0.f, 0.f};

    for (int kc = 0; kc < 8; kc++) {
        __syncthreads();
        for (int idx = tid; idx < 50 * 16; idx += 256) {
            int r = idx >> 4, g = idx & 15;
            int gp = p0 + r;
            float4 v = make_float4(0.f, 0.f, 0.f, 0.f);
            if (gp >= 0 && gp < 1920)
                v = *(const float4*)(x + (size_t)gp * 512 + kc * 64 + 4 * g);
            short* d = xs + r * 72 + 4 * g;
            d[0] = f2bf(v.x); d[1] = f2bf(v.y); d[2] = f2bf(v.z); d[3] = f2bf(v.w);
        }
        __syncthreads();

        #pragma unroll
        for (int ks = 0; ks < 10; ks++) {
            int kw  = ks >> 1;
            int ci0 = (ks & 1) * 32;
            short8 a = *(const short8*)(xs + (3 * mrow + kw) * 72 + ci0 + quad * 8);
            #pragma unroll
            for (int ni = 0; ni < 2; ni++) {
                short8 b = *(const short8*)(w1s +
                    ((((size_t)kc * 10 + ks) * 8 + (w * 2 + ni)) * 64 + lane) * 8);
                acc[ni] = __builtin_amdgcn_mfma_f32_16x16x32_bf16(a, b, acc[ni], 0, 0, 0);
            }
        }
    }

    // ---- epilogue: bias1, LN1 over 128 co, SiLU, bf16 store
    float b1v[2], g1v[2], btv[2];
    #pragma unroll
    for (int ni = 0; ni < 2; ni++) {
        int co = w * 32 + ni * 16 + mrow;
        b1v[ni] = b1[co]; g1v[ni] = g1[co]; btv[ni] = bt1[co];
    }

    float s1[4] = {0.f, 0.f, 0.f, 0.f}, s2[4] = {0.f, 0.f, 0.f, 0.f};
    #pragma unroll
    for (int ni = 0; ni < 2; ni++)
        #pragma unroll
        for (int r = 0; r < 4; r++) {
            float v = acc[ni][r] + b1v[ni];
            acc[ni][r] = v;
            s1[r] += v; s2[r] += v * v;
        }
    #pragma unroll
    for (int m = 8; m >= 1; m >>= 1) {
        #pragma unroll
        for (int r = 0; r < 4; r++) {
            s1[r] += __shfl_xor(s1[r], m, 64);
            s2[r] += __shfl_xor(s2[r], m, 64);
        }
    }
    if (mrow == 0) {
        #pragma unroll
        for (int r = 0; r < 4; r++) { red[w][quad][r][0] = s1[r]; red[w][quad][r][1] = s2[r]; }
    }
    __syncthreads();

    #pragma unroll
    for (int r = 0; r < 4; r++) {
        float S1 = red[0][quad][r][0] + red[1][quad][r][0]
                 + red[2][quad][r][0] + red[3][quad][r][0];
        float S2 = red[0][quad][r][1] + red[1][quad][r][1]
                 + red[2][quad][r][1] + red[3][quad][r][1];
        float mean = S1 * (1.f / 128.f);
        float var  = S2 * (1.f / 128.f) - mean * mean;
        float rs   = rsqrtf(var + LN_EPS);
        int row = seq * 640 + tl * 16 + quad * 4 + r;
        #pragma unroll
        for (int ni = 0; ni < 2; ni++) {
            float o = silu_f((acc[ni][r] - mean) * rs * g1v[ni] + btv[ni]);
            h1[(size_t)row * 128 + w * 32 + ni * 16 + mrow] = f2bf(o);
        }
    }
}

// ---------------- Kernel 2: conv2 MFMA (16 pos x 1024 co) + LN2 + SiLU -> vp/sp
// grid = 40 blocks, 256 threads (4 waves, n-split 256 co each).
__global__ __launch_bounds__(256) void k_conv2m(
    const short* __restrict__ h1,    // (3200,128) bf16
    const short* __restrict__ w2s,
    const float* __restrict__ b2,
    const float* __restrict__ g2,
    const float* __restrict__ bt2,
    float* __restrict__ vp,          // (512,1024)
    float* __restrict__ sp)          // (128,1024)
{
    int blk  = blockIdx.x;           // 0..39
    int pos0 = blk * 16;             // global out pos
    int seq  = pos0 >> 7;
    int lcl0 = pos0 & 127;
    int row0 = seq * 640 + 5 * lcl0;

    __shared__ short xa[78 * 136];
    __shared__ float red[4][4][4][2];

    int tid = threadIdx.x;

    // staging: plain bf16 copy, 78 rows x 128 ci
    for (int idx = tid; idx < 78 * 16; idx += 256) {
        int r = idx >> 4, g = idx & 15;
        *(short8*)(xa + r * 136 + g * 8) =
            *(const short8*)(h1 + (size_t)(row0 + r) * 128 + g * 8);
    }
    __syncthreads();

    int lane = tid & 63, w = tid >> 6;
    int quad = lane >> 4, mrow = lane & 15;

    floatx4 acc[16];
    #pragma unroll
    for (int nt = 0; nt < 16; nt++) acc[nt] = (floatx4){0.f, 0.f, 0.f, 0.f};

    #pragma unroll 3
    for (int ks = 0; ks < 12; ks++) {
        int kw  = ks >> 2;
        int ci0 = (ks & 3) * 32;
        short8 a = *(const short8*)(xa + (5 * mrow + kw) * 136 + ci0 + quad * 8);
        #pragma unroll
        for (int nt = 0; nt < 16; nt++) {
            short8 b = *(const short8*)(w2s +
                (((size_t)ks * 64 + w * 16 + nt) * 64 + lane) * 8);
            acc[nt] = __builtin_amdgcn_mfma_f32_16x16x32_bf16(a, b, acc[nt], 0, 0, 0);
        }
    }

    // epilogue: bias2, LN2 over 1024, SiLU, store
    float b2v[16], g2v[16], btv[16];
    #pragma unroll
    for (int nt = 0; nt < 16; nt++) {
        int co = w * 256 + nt * 16 + mrow;
        b2v[nt] = b2[co]; g2v[nt] = g2[co]; btv[nt] = bt2[co];
    }

    float s1[4] = {0.f, 0.f, 0.f, 0.f}, s2[4] = {0.f, 0.f, 0.f, 0.f};
    #pragma unroll
    for (int nt = 0; nt < 16; nt++)
        #pragma unroll
        for (int r = 0; r < 4; r++) {
            float v = acc[nt][r] + b2v[nt];
            acc[nt][r] = v;
            s1[r] += v; s2[r] += v * v;
        }
    #pragma unroll
    for (int m = 8; m >= 1; m >>= 1) {
        #pragma unroll
        for (int r = 0; r < 4; r++) {
            s1[r] += __shfl_xor(s1[r], m, 64);
            s2[r] += __shfl_xor(s2[r], m, 64);
        }
    }
    if (mrow == 0) {
        #pragma unroll
        for (int r = 0; r < 4; r++) { red[w][quad][r][0] = s1[r]; red[w][quad][r][1] = s2[r]; }
    }
    __syncthreads();

    float mean[4], rs[4];
    #pragma unroll
    for (int r = 0; r < 4; r++) {
        float S1 = red[0][quad][r][0] + red[1][quad][r][0]
                 + red[2][quad][r][0] + red[3][quad][r][0];
        float S2 = red[0][quad][r][1] + red[1][quad][r][1]
                 + red[2][quad][r][1] + red[3][quad][r][1];
        mean[r] = S1 * (1.f / 1024.f);
        float var = S2 * (1.f / 1024.f) - mean[r] * mean[r];
        rs[r] = rsqrtf(var + LN_EPS);
    }

    float* obase = (pos0 < 512) ? (vp + (size_t)pos0 * 1024)
                                : (sp + (size_t)(pos0 - 512) * 1024);
    #pragma unroll
    for (int nt = 0; nt < 16; nt++) {
        int co = w * 256 + nt * 16 + mrow;
        #pragma unroll
        for (int r = 0; r < 4; r++) {
            float o = silu_f((acc[nt][r] - mean[r]) * rs[r] * g2v[nt] + btv[nt]);
            obase[((size_t)(quad * 4 + r)) * 1024 + co] = o;
        }
    }
}

// ---------------- Kernel 3: fused attention, 2 j's per block
// grid = 4b * 64 jpairs = 256 blocks, 256 threads.
__global__ __launch_bounds__(256) void k_attn(
    const float* __restrict__ vp,   // (512,1024)
    const float* __restrict__ sp,   // (128,1024)
    float* __restrict__ O)          // (4,128,1024)
{
    int b  = blockIdx.x >> 6;
    int j0 = (blockIdx.x & 63) * 2;
    int tid = threadIdx.x, lane = tid & 63, wv = tid >> 6;

    __shared__ int   cc[2][128][2];
    __shared__ float sc0[128], sc1[128];
    __shared__ float redm[2][4], reds[2][4];

    // phase 1: mismatch counts, register-accumulated
    {
        int i = tid & 127, half = tid >> 7;
        const float* vrow = vp + ((size_t)(b * 128 + i)) * 1024 + half * 512;
        const float* s0r  = sp + (size_t)j0 * 1024 + half * 512;
        const float* s1r  = s0r + 1024;
        int m0 = 0, m1 = 0;
        #pragma unroll 8
        for (int k = 0; k < 128; k++) {
            float4 v  = *(const float4*)(vrow + 4 * k);
            float4 s0 = *(const float4*)(s0r + 4 * k);
            float4 s1 = *(const float4*)(s1r + 4 * k);
            m0 += mism1(v.x, s0.x) + mism1(v.y, s0.y) + mism1(v.z, s0.z) + mism1(v.w, s0.w);
            m1 += mism1(v.x, s1.x) + mism1(v.y, s1.y) + mism1(v.z, s1.z) + mism1(v.w, s1.w);
        }
        cc[half][i][0] = m0;
        cc[half][i][1] = m1;
    }
    __syncthreads();

    // softmax over i=128 for both j's
    float S0v = -INFINITY, S1v = -INFINITY;
    if (tid < 128) {
        int c0 = cc[0][tid][0] + cc[1][tid][0];
        int c1 = cc[0][tid][1] + cc[1][tid][1];
        S0v = 1.f - (float)c0 * (2.f / 1024.f);
        S1v = 1.f - (float)c1 * (2.f / 1024.f);
    }
    float m0v = S0v, m1v = S1v;
    #pragma unroll
    for (int m = 32; m >= 1; m >>= 1) {
        m0v = fmaxf(m0v, __shfl_xor(m0v, m, 64));
        m1v = fmaxf(m1v, __shfl_xor(m1v, m, 64));
    }
    if (lane == 0) { redm[0][wv] = m0v; redm[1][wv] = m1v; }
    __syncthreads();
    float mx0 = fmaxf(fmaxf(redm[0][0], redm[0][1]), fmaxf(redm[0][2], redm[0][3]));
    float mx1 = fmaxf(fmaxf(redm[1][0], redm[1][1]), fmaxf(redm[1][2], redm[1][3]));

    float e0 = (tid < 128) ? expf(S0v - mx0) : 0.f;
    float e1 = (tid < 128) ? expf(S1v - mx1) : 0.f;
    float t0 = e0, t1 = e1;
    #pragma unroll
    for (int m = 32; m >= 1; m >>= 1) {
        t0 += __shfl_xor(t0, m, 64);
        t1 += __shfl_xor(t1, m, 64);
    }
    if (lane == 0) { reds[0][wv] = t0; reds[1][wv] = t1; }
    __syncthreads();
    float tot0 = reds[0][0] + reds[0][1] + reds[0][2] + reds[0][3];
    float tot1 = reds[1][0] + reds[1][1] + reds[1][2] + reds[1][3];
    if (tid < 128) { sc0[tid] = e0 / tot0; sc1[tid] = e1 / tot1; }
    __syncthreads();

    // phase 2: einsum + silu for both j's
    int dd = 4 * tid;
    const float* vpb = vp + (size_t)b * 131072;
    float4 ao0 = make_float4(0.f, 0.f, 0.f, 0.f);
    float4 ao1 = make_float4(0.f, 0.f, 0.f, 0.f);
    #pragma unroll 4
    for (int i = 0; i < 128; i++) {
        float4 v = *(const float4*)(vpb + (size_t)i * 1024 + dd);
        float f0 = sc0[i], f1 = sc1[i];
        ao0.x += f0 * v.x; ao0.y += f0 * v.y; ao0.z += f0 * v.z; ao0.w += f0 * v.w;
        ao1.x += f1 * v.x; ao1.y += f1 * v.y; ao1.z += f1 * v.z; ao1.w += f1 * v.w;
    }
    float4 s0 = *(const float4*)(sp + (size_t)j0 * 1024 + dd);
    float4 s1 = *(const float4*)(sp + (size_t)(j0 + 1) * 1024 + dd);
    float4 o0, o1;
    o0.x = silu_f(ao0.x * s0.x); o0.y = silu_f(ao0.y * s0.y);
    o0.z = silu_f(ao0.z * s0.z); o0.w = silu_f(ao0.w * s0.w);
    o1.x = silu_f(ao1.x * s1.x); o1.y = silu_f(ao1.y * s1.y);
    o1.z = silu_f(ao1.z * s1.z); o1.w = silu_f(ao1.w * s1.w);
    *(float4*)(O + ((size_t)b * 128 + j0)     * 1024 + dd) = o0;
    *(float4*)(O + ((size_t)b * 128 + j0 + 1) * 1024 + dd) = o1;
}

extern "C" void kernel_launch(void* const* d_in, const int* in_sizes, int n_in,
                              void* d_out, int out_size, void* d_ws, size_t ws_size,
                              hipStream_t stream) {
    const float* values  = (const float*)d_in[0];
    const float* symbols = (const float*)d_in[1];
    const float* conv1_w = (const float*)d_in[2];
    const float* conv1_b = (const float*)d_in[3];
    const float* ln1_g   = (const float*)d_in[4];
    const float* ln1_b   = (const float*)d_in[5];
    const float* conv2_w = (const float*)d_in[6];
    const float* conv2_b = (const float*)d_in[7];
    const float* ln2_g   = (const float*)d_in[8];
    const float* ln2_b   = (const float*)d_in[9];

    float* out = (float*)d_out;
    float* O   = out;                       // (4,128,1024)
    float* vp  = out + 4 * 128 * 1024;      // (4,128,1024)

    float* sp  = (float*)d_ws;              // (128,1024) f32
    short* h1  = (short*)(sp + 128 * 1024); // (3200,128) bf16
    short* w1s = h1 + 3200 * 128;           // 327,680
    short* w2s = w1s + 327680;              // 393,216

    k_prep<<<2816, 256, 0, stream>>>(conv1_w, conv2_w, w1s, w2s);
    k_conv1m<<<200, 256, 0, stream>>>(values, symbols, w1s,
                                      conv1_b, ln1_g, ln1_b, h1);
    k_conv2m<<<40, 256, 0, stream>>>(h1, w2s, conv2_b, ln2_g, ln2_b, vp, sp);
    k_attn<<<256, 256, 0, stream>>>(vp, sp, O);
}

// Round 8
// 175.585 us; speedup vs baseline: 1.1559x; 1.0166x over previous
//
#include <hip/hip_runtime.h>
#include <math.h>

#define LN_EPS 1e-3f

typedef __attribute__((ext_vector_type(8))) short short8;
typedef __attribute__((ext_vector_type(4))) float floatx4;

__device__ __forceinline__ float silu_f(float x) { return x / (1.f + expf(-x)); }

__device__ __forceinline__ int mism1(float a, float s) {
    unsigned ua = __float_as_uint(a);
    unsigned ub = __float_as_uint(a + s);
    return (int)((ua ^ ub) >> 31);
}

__device__ __forceinline__ short f2bf(float f) {
    unsigned u = __float_as_uint(f);
    unsigned r = (u + 0x7FFFu + ((u >> 16) & 1u)) >> 16;
    return (short)r;
}

// ---------------- Kernel 0: swizzle conv1 + conv2 weights into B-fragment bf16
__global__ __launch_bounds__(256) void k_prep(
    const float* __restrict__ w1,   // (5,512,128)
    const float* __restrict__ w2,   // (3,128,1024)
    short* __restrict__ w1s,
    short* __restrict__ w2s)
{
    int tid = blockIdx.x * 256 + threadIdx.x;
    if (tid < 327680) {
        int j    = tid & 7;
        int lane = (tid >> 3) & 63;
        int nt   = (tid >> 9) & 7;
        int ks   = (tid >> 12) % 10;
        int kc   = tid / 40960;
        int kw = ks >> 1;
        int ci = kc * 64 + (ks & 1) * 32 + ((lane >> 4) & 3) * 8 + j;
        int n  = nt * 16 + (lane & 15);
        w1s[tid] = f2bf(w1[((size_t)(kw * 512 + ci)) * 128 + n]);
    } else {
        int t = tid - 327680;
        if (t < 393216) {
            int j    = t & 7;
            int lane = (t >> 3) & 63;
            int nt   = (t >> 9) & 63;
            int ks   = t >> 15;                 // 0..11
            int k  = ks * 32 + ((lane >> 4) & 3) * 8 + j;   // 0..383
            int kw = k >> 7;
            int ci = k & 127;
            int n  = nt * 16 + (lane & 15);
            w2s[t] = f2bf(w2[((size_t)(kw * 128 + ci)) * 1024 + n]);
        }
    }
}

// ---------------- Kernel 1: conv1 full-K MFMA GEMM + bias + LN1(128) + SiLU -> h1 bf16
// grid = 200 blocks (5 seq * 40 tiles of 16 pos), 256 threads (4 waves).
__global__ __launch_bounds__(256) void k_conv1m(
    const float* __restrict__ values,   // (4,1920,512)
    const float* __restrict__ symbols,  // (1920,512)
    const short* __restrict__ w1s,
    const float* __restrict__ b1,
    const float* __restrict__ g1,
    const float* __restrict__ bt1,
    short* __restrict__ h1)             // (3200,128) bf16
{
    int mt  = blockIdx.x;               // 0..199
    int seq = mt / 40;
    int tl  = mt % 40;
    const float* x = (seq < 4) ? (values + (size_t)seq * 1920 * 512) : symbols;
    int p0 = 3 * (tl * 16) - 1;

    __shared__ short xs[50 * 72];
    __shared__ float red[4][4][4][2];

    int tid  = threadIdx.x;
    int lane = tid & 63, w = tid >> 6;
    int quad = lane >> 4, mrow = lane & 15;

    floatx4 acc[2];
    acc[0] = (floatx4){0.f, 0.f, 0.f, 0.f};
    acc[1] = (floatx4){0.f, 0.f, 0.f, 0.f};

    for (int kc = 0; kc < 8; kc++) {
        __syncthreads();
        for (int idx = tid; idx < 50 * 16; idx += 256) {
            int r = idx >> 4, g = idx & 15;
            int gp = p0 + r;
            float4 v = make_float4(0.f, 0.f, 0.f, 0.f);
            if (gp >= 0 && gp < 1920)
                v = *(const float4*)(x + (size_t)gp * 512 + kc * 64 + 4 * g);
            short* d = xs + r * 72 + 4 * g;
            d[0] = f2bf(v.x); d[1] = f2bf(v.y); d[2] = f2bf(v.z); d[3] = f2bf(v.w);
        }
        __syncthreads();

        #pragma unroll
        for (int ks = 0; ks < 10; ks++) {
            int kw  = ks >> 1;
            int ci0 = (ks & 1) * 32;
            short8 a = *(const short8*)(xs + (3 * mrow + kw) * 72 + ci0 + quad * 8);
            #pragma unroll
            for (int ni = 0; ni < 2; ni++) {
                short8 b = *(const short8*)(w1s +
                    ((((size_t)kc * 10 + ks) * 8 + (w * 2 + ni)) * 64 + lane) * 8);
                acc[ni] = __builtin_amdgcn_mfma_f32_16x16x32_bf16(a, b, acc[ni], 0, 0, 0);
            }
        }
    }

    float b1v[2], g1v[2], btv[2];
    #pragma unroll
    for (int ni = 0; ni < 2; ni++) {
        int co = w * 32 + ni * 16 + mrow;
        b1v[ni] = b1[co]; g1v[ni] = g1[co]; btv[ni] = bt1[co];
    }

    float s1[4] = {0.f, 0.f, 0.f, 0.f}, s2[4] = {0.f, 0.f, 0.f, 0.f};
    #pragma unroll
    for (int ni = 0; ni < 2; ni++)
        #pragma unroll
        for (int r = 0; r < 4; r++) {
            float v = acc[ni][r] + b1v[ni];
            acc[ni][r] = v;
            s1[r] += v; s2[r] += v * v;
        }
    #pragma unroll
    for (int m = 8; m >= 1; m >>= 1) {
        #pragma unroll
        for (int r = 0; r < 4; r++) {
            s1[r] += __shfl_xor(s1[r], m, 64);
            s2[r] += __shfl_xor(s2[r], m, 64);
        }
    }
    if (mrow == 0) {
        #pragma unroll
        for (int r = 0; r < 4; r++) { red[w][quad][r][0] = s1[r]; red[w][quad][r][1] = s2[r]; }
    }
    __syncthreads();

    #pragma unroll
    for (int r = 0; r < 4; r++) {
        float S1 = red[0][quad][r][0] + red[1][quad][r][0]
                 + red[2][quad][r][0] + red[3][quad][r][0];
        float S2 = red[0][quad][r][1] + red[1][quad][r][1]
                 + red[2][quad][r][1] + red[3][quad][r][1];
        float mean = S1 * (1.f / 128.f);
        float var  = S2 * (1.f / 128.f) - mean * mean;
        float rs   = rsqrtf(var + LN_EPS);
        int row = seq * 640 + tl * 16 + quad * 4 + r;
        #pragma unroll
        for (int ni = 0; ni < 2; ni++) {
            float o = silu_f((acc[ni][r] - mean) * rs * g1v[ni] + btv[ni]);
            h1[(size_t)row * 128 + w * 32 + ni * 16 + mrow] = f2bf(o);
        }
    }
}

// ---------------- Kernel 2: conv2 MFMA (16 pos x 1024 co) + LN2 + SiLU -> vp/sp
__global__ __launch_bounds__(256) void k_conv2m(
    const short* __restrict__ h1,    // (3200,128) bf16
    const short* __restrict__ w2s,
    const float* __restrict__ b2,
    const float* __restrict__ g2,
    const float* __restrict__ bt2,
    float* __restrict__ vp,          // (512,1024)
    float* __restrict__ sp)          // (128,1024)
{
    int blk  = blockIdx.x;           // 0..39
    int pos0 = blk * 16;
    int seq  = pos0 >> 7;
    int lcl0 = pos0 & 127;
    int row0 = seq * 640 + 5 * lcl0;

    __shared__ short xa[78 * 136];
    __shared__ float red[4][4][4][2];

    int tid = threadIdx.x;

    for (int idx = tid; idx < 78 * 16; idx += 256) {
        int r = idx >> 4, g = idx & 15;
        *(short8*)(xa + r * 136 + g * 8) =
            *(const short8*)(h1 + (size_t)(row0 + r) * 128 + g * 8);
    }
    __syncthreads();

    int lane = tid & 63, w = tid >> 6;
    int quad = lane >> 4, mrow = lane & 15;

    floatx4 acc[16];
    #pragma unroll
    for (int nt = 0; nt < 16; nt++) acc[nt] = (floatx4){0.f, 0.f, 0.f, 0.f};

    #pragma unroll 3
    for (int ks = 0; ks < 12; ks++) {
        int kw  = ks >> 2;
        int ci0 = (ks & 3) * 32;
        short8 a = *(const short8*)(xa + (5 * mrow + kw) * 136 + ci0 + quad * 8);
        #pragma unroll
        for (int nt = 0; nt < 16; nt++) {
            short8 b = *(const short8*)(w2s +
                (((size_t)ks * 64 + w * 16 + nt) * 64 + lane) * 8);
            acc[nt] = __builtin_amdgcn_mfma_f32_16x16x32_bf16(a, b, acc[nt], 0, 0, 0);
        }
    }

    float b2v[16], g2v[16], btv[16];
    #pragma unroll
    for (int nt = 0; nt < 16; nt++) {
        int co = w * 256 + nt * 16 + mrow;
        b2v[nt] = b2[co]; g2v[nt] = g2[co]; btv[nt] = bt2[co];
    }

    float s1[4] = {0.f, 0.f, 0.f, 0.f}, s2[4] = {0.f, 0.f, 0.f, 0.f};
    #pragma unroll
    for (int nt = 0; nt < 16; nt++)
        #pragma unroll
        for (int r = 0; r < 4; r++) {
            float v = acc[nt][r] + b2v[nt];
            acc[nt][r] = v;
            s1[r] += v; s2[r] += v * v;
        }
    #pragma unroll
    for (int m = 8; m >= 1; m >>= 1) {
        #pragma unroll
        for (int r = 0; r < 4; r++) {
            s1[r] += __shfl_xor(s1[r], m, 64);
            s2[r] += __shfl_xor(s2[r], m, 64);
        }
    }
    if (mrow == 0) {
        #pragma unroll
        for (int r = 0; r < 4; r++) { red[w][quad][r][0] = s1[r]; red[w][quad][r][1] = s2[r]; }
    }
    __syncthreads();

    float mean[4], rs[4];
    #pragma unroll
    for (int r = 0; r < 4; r++) {
        float S1 = red[0][quad][r][0] + red[1][quad][r][0]
                 + red[2][quad][r][0] + red[3][quad][r][0];
        float S2 = red[0][quad][r][1] + red[1][quad][r][1]
                 + red[2][quad][r][1] + red[3][quad][r][1];
        mean[r] = S1 * (1.f / 1024.f);
        float var = S2 * (1.f / 1024.f) - mean[r] * mean[r];
        rs[r] = rsqrtf(var + LN_EPS);
    }

    float* obase = (pos0 < 512) ? (vp + (size_t)pos0 * 1024)
                                : (sp + (size_t)(pos0 - 512) * 1024);
    #pragma unroll
    for (int nt = 0; nt < 16; nt++) {
        int co = w * 256 + nt * 16 + mrow;
        #pragma unroll
        for (int r = 0; r < 4; r++) {
            float o = silu_f((acc[nt][r] - mean[r]) * rs[r] * g2v[nt] + btv[nt]);
            obase[((size_t)(quad * 4 + r)) * 1024 + co] = o;
        }
    }
}

// ---------------- Kernel 3: mismatch counts, 2 j's per block, d-half split
// grid = 4b * 64 jpair * 2 half = 512 blocks, 256 threads.
// thread = (i = tid&127, sub = tid>>7): scans d in [half*512 + sub*256, +256).
__global__ __launch_bounds__(256) void k_attn_cnt(
    const float* __restrict__ vp,   // (512,1024)
    const float* __restrict__ sp,   // (128,1024)
    int* __restrict__ cnt2)         // (4,64,2,2,128): b, jp, jj, half, i
{
    int half = blockIdx.x & 1;
    int jp   = (blockIdx.x >> 1) & 63;
    int b    = blockIdx.x >> 7;
    int j0   = jp * 2;
    int tid = threadIdx.x;
    int i = tid & 127, sub = tid >> 7;
    int d0 = half * 512 + sub * 256;

    const float* vrow = vp + ((size_t)(b * 128 + i)) * 1024 + d0;
    const float* s0r  = sp + (size_t)j0 * 1024 + d0;
    const float* s1r  = s0r + 1024;

    int m0 = 0, m1 = 0;
    #pragma unroll 8
    for (int k = 0; k < 64; k++) {
        float4 v  = *(const float4*)(vrow + 4 * k);
        float4 s0 = *(const float4*)(s0r + 4 * k);
        float4 s1 = *(const float4*)(s1r + 4 * k);
        m0 += mism1(v.x, s0.x) + mism1(v.y, s0.y) + mism1(v.z, s0.z) + mism1(v.w, s0.w);
        m1 += mism1(v.x, s1.x) + mism1(v.y, s1.y) + mism1(v.z, s1.z) + mism1(v.w, s1.w);
    }

    __shared__ int cc[2][128][2];
    if (sub == 0) { cc[0][i][0] = m0; cc[0][i][1] = m1; }
    __syncthreads();
    if (sub == 1) { cc[1][i][0] = m0; cc[1][i][1] = m1; }
    __syncthreads();

    if (tid < 128) {
        int base = (((b * 64 + jp) * 2 + 0) * 2 + half) * 128;
        cnt2[base + tid] = cc[0][tid][0] + cc[1][tid][0];
        cnt2[base + 256 + tid] = cc[0][tid][1] + cc[1][tid][1];  // jj=1
    }
}

// ---------------- Kernel 4: softmax + einsum + silu, 2 j's per block, d-half split
// grid = 4b * 64 jpair * 2 half = 512 blocks, 256 threads.
__global__ __launch_bounds__(256) void k_attn_out(
    const int*   __restrict__ cnt2, // (4,64,2,2,128)
    const float* __restrict__ vp,   // (512,1024)
    const float* __restrict__ sp,   // (128,1024)
    float* __restrict__ O)          // (4,128,1024)
{
    int half = blockIdx.x & 1;
    int jp   = (blockIdx.x >> 1) & 63;
    int b    = blockIdx.x >> 7;
    int j0   = jp * 2;
    int tid = threadIdx.x, lane = tid & 63, wv = tid >> 6;

    __shared__ float sc[2][128];
    __shared__ float redm[2][2], reds[2][2];

    // softmax: wave wv handles jj = wv>>1, i-half ih = wv&1
    {
        int jj = wv >> 1, ih = wv & 1;
        int i = ih * 64 + lane;
        int c = cnt2[((((b * 64 + jp) * 2 + jj) * 2 + 0) * 128) + i]
              + cnt2[((((b * 64 + jp) * 2 + jj) * 2 + 1) * 128) + i];
        float S = 1.f - (float)c * (2.f / 1024.f);
        float mx = S;
        #pragma unroll
        for (int m = 32; m >= 1; m >>= 1) mx = fmaxf(mx, __shfl_xor(mx, m, 64));
        if (lane == 0) redm[jj][ih] = mx;
        __syncthreads();
        float MX = fmaxf(redm[jj][0], redm[jj][1]);
        float e = expf(S - MX);
        float sm = e;
        #pragma unroll
        for (int m = 32; m >= 1; m >>= 1) sm += __shfl_xor(sm, m, 64);
        if (lane == 0) reds[jj][ih] = sm;
        sc[jj][i] = e;
        __syncthreads();
    }

    int jj   = tid >> 7;           // 0 or 1
    int dloc = tid & 127;
    int dd   = half * 512 + 4 * dloc;
    int j    = j0 + jj;
    float inv = 1.f / (reds[jj][0] + reds[jj][1]);

    const float* vpb = vp + (size_t)b * 131072;
    float4 ao = make_float4(0.f, 0.f, 0.f, 0.f);
    #pragma unroll 4
    for (int i = 0; i < 128; i++) {
        float4 v = *(const float4*)(vpb + (size_t)i * 1024 + dd);
        float f = sc[jj][i];
        ao.x += f * v.x; ao.y += f * v.y; ao.z += f * v.z; ao.w += f * v.w;
    }
    float4 s = *(const float4*)(sp + (size_t)j * 1024 + dd);
    float4 o;
    o.x = silu_f(ao.x * inv * s.x);
    o.y = silu_f(ao.y * inv * s.y);
    o.z = silu_f(ao.z * inv * s.z);
    o.w = silu_f(ao.w * inv * s.w);
    *(float4*)(O + ((size_t)b * 128 + j) * 1024 + dd) = o;
}

extern "C" void kernel_launch(void* const* d_in, const int* in_sizes, int n_in,
                              void* d_out, int out_size, void* d_ws, size_t ws_size,
                              hipStream_t stream) {
    const float* values  = (const float*)d_in[0];
    const float* symbols = (const float*)d_in[1];
    const float* conv1_w = (const float*)d_in[2];
    const float* conv1_b = (const float*)d_in[3];
    const float* ln1_g   = (const float*)d_in[4];
    const float* ln1_b   = (const float*)d_in[5];
    const float* conv2_w = (const float*)d_in[6];
    const float* conv2_b = (const float*)d_in[7];
    const float* ln2_g   = (const float*)d_in[8];
    const float* ln2_b   = (const float*)d_in[9];

    float* out = (float*)d_out;
    float* O   = out;                       // (4,128,1024)
    float* vp  = out + 4 * 128 * 1024;      // (4,128,1024)

    float* sp   = (float*)d_ws;              // (128,1024) f32
    short* h1   = (short*)(sp + 128 * 1024); // (3200,128) bf16
    short* w1s  = h1 + 3200 * 128;           // 327,680
    short* w2s  = w1s + 327680;              // 393,216
    int*   cnt2 = (int*)(w2s + 393216);      // 4*64*2*2*128 = 131,072 ints

    k_prep<<<2816, 256, 0, stream>>>(conv1_w, conv2_w, w1s, w2s);
    k_conv1m<<<200, 256, 0, stream>>>(values, symbols, w1s,
                                      conv1_b, ln1_g, ln1_b, h1);
    k_conv2m<<<40, 256, 0, stream>>>(h1, w2s, conv2_b, ln2_g, ln2_b, vp, sp);
    k_attn_cnt<<<512, 256, 0, stream>>>(vp, sp, cnt2);
    k_attn_out<<<512, 256, 0, stream>>>(cnt2, vp, sp, O);
}